// Round 1
// baseline (241.916 us; speedup 1.0000x reference)
//
#include <hip/hip_runtime.h>
#include <math.h>

#define NB 4096
#define PAD 2048
#define BLOCK 256

__device__ __forceinline__ int mirror_idx(int i) {
    // valid for i in [-PAD, NB+PAD-2]; single reflection
    i = ::abs(i);
    return (i < NB) ? i : (2 * (NB - 1) - i);
}

// Precompute p = sigmoid(logits), lsp = log_sigmoid(logits), lsn = log_sigmoid(-logits)
// into ws[0..NB), ws[NB..2NB), ws[2NB..3NB).
__global__ void fbmp_precompute(const float* __restrict__ logits, float* __restrict__ ws) {
    int j = blockIdx.x * blockDim.x + threadIdx.x;
    if (j >= NB) return;
    float x = logits[j];
    double xd = (double)x;
    // correctly-rounded f32 exp(-x), then the fp32 1/(1+e) pipeline:
    // best-effort bit-match of the reference's exp-based logistic.
    float e = (float)exp(-xd);
    float p = 1.0f / (1.0f + e);
    float lsp = (float)(-log1p(exp(-xd)));  // log_sigmoid(x)
    float lsn = (float)(-log1p(exp(xd)));   // log_sigmoid(-x)
    ws[j] = p;
    ws[NB + j] = lsp;
    ws[2 * NB + j] = lsn;
}

__global__ __launch_bounds__(BLOCK) void fbmp_main(
    const float* __restrict__ u, const int* __restrict__ shift,
    const float* __restrict__ ws,
    float* __restrict__ masks, float* __restrict__ logp)
{
    __shared__ float sg[NB];            // this row's grid bits (as float)
    __shared__ float sred[BLOCK / 64];  // per-wave partial sums

    const int b = blockIdx.x;
    const float4* __restrict__ u4   = (const float4*)(u + (size_t)b * NB);
    const float4* __restrict__ p4   = (const float4*)(ws);
    const float4* __restrict__ lsp4 = (const float4*)(ws + NB);
    const float4* __restrict__ lsn4 = (const float4*)(ws + 2 * NB);

    float acc = 0.0f;
    // NB/4 = 1024 float4s; 256 threads -> 4 uniform iterations
    for (int i = threadIdx.x; i < NB / 4; i += BLOCK) {
        float4 uv = u4[i];
        float4 pv = p4[i];
        float4 ap = lsp4[i];
        float4 an = lsn4[i];
        bool c0 = uv.x < pv.x;
        bool c1 = uv.y < pv.y;
        bool c2 = uv.z < pv.z;
        bool c3 = uv.w < pv.w;
        acc += (c0 ? ap.x : an.x) + (c1 ? ap.y : an.y)
             + (c2 ? ap.z : an.z) + (c3 ? ap.w : an.w);
        float4 g;
        g.x = c0 ? 1.0f : 0.0f;
        g.y = c1 ? 1.0f : 0.0f;
        g.z = c2 ? 1.0f : 0.0f;
        g.w = c3 ? 1.0f : 0.0f;
        ((float4*)sg)[i] = g;
    }

    // block reduction of acc -> logp[b]
    #pragma unroll
    for (int off = 32; off > 0; off >>= 1)
        acc += __shfl_down(acc, off, 64);
    const int lane = threadIdx.x & 63;
    const int wid  = threadIdx.x >> 6;
    if (lane == 0) sred[wid] = acc;
    __syncthreads();   // also publishes sg for the gather below
    if (threadIdx.x == 0) {
        float t = 0.0f;
        #pragma unroll
        for (int w = 0; w < BLOCK / 64; ++w) t += sred[w];
        logp[b] = t;
    }

    // reflect-pad + shifted-window gather: masks[b][k] = grid[b][mirror(shift+k-PAD)]
    const int s = shift[b] - PAD;
    float4* __restrict__ m4 = (float4*)(masks + (size_t)b * NB);
    for (int i = threadIdx.x; i < NB / 4; i += BLOCK) {
        int k = 4 * i + s;
        float4 o;
        o.x = sg[mirror_idx(k + 0)];
        o.y = sg[mirror_idx(k + 1)];
        o.z = sg[mirror_idx(k + 2)];
        o.w = sg[mirror_idx(k + 3)];
        m4[i] = o;
    }
}

extern "C" void kernel_launch(void* const* d_in, const int* in_sizes, int n_in,
                              void* d_out, int out_size, void* d_ws, size_t ws_size,
                              hipStream_t stream) {
    const float* logits = (const float*)d_in[0];
    const float* u      = (const float*)d_in[1];
    const int*   shift  = (const int*)d_in[2];
    const int B = in_sizes[2];

    float* ws    = (float*)d_ws;                    // 3*NB floats
    float* masks = (float*)d_out;                   // B*NB
    float* logp  = (float*)d_out + (size_t)B * NB;  // B

    fbmp_precompute<<<(NB + 255) / 256, 256, 0, stream>>>(logits, ws);
    fbmp_main<<<B, BLOCK, 0, stream>>>(u, shift, ws, masks, logp);
}